// Round 1
// baseline (749.076 us; speedup 1.0000x reference)
//
#include <hip/hip_runtime.h>
#include <math.h>

// Problem constants (fixed by reference)
#define NR 2048
#define MC 131072
#define DIM 64
#define KSEL 11                    // k+1 smallest kept per row
#define PPART 64                   // column partitions
#define PART_COLS (MC / PPART)     // 2048 cols per partition
#define CHUNK 128                  // cols per LDS chunk
#define NCHUNK (PART_COLS / CHUNK) // 16
#define CAP 32                     // per-row candidate bucket capacity
#define BSTRIDE 72                 // padded f16 row stride in LDS (144B, 16B-aligned)

typedef _Float16 v8h __attribute__((ext_vector_type(8)));
typedef float v4f __attribute__((ext_vector_type(4)));

// ---------------- prep: bnorm (fp32) + buf -> f16 ----------------
__global__ __launch_bounds__(256) void k_prep_b(const float* __restrict__ buf,
                                                _Float16* __restrict__ B16,
                                                float* __restrict__ bnorm) {
  int gid = blockIdx.x * 256 + threadIdx.x;   // 4 threads per buffer row
  int row = gid >> 2, q = gid & 3;
  const float4* src = (const float4*)(buf + (size_t)row * DIM + q * 16);
  float4 f0 = src[0], f1 = src[1], f2 = src[2], f3 = src[3];
  float s = f0.x*f0.x + f0.y*f0.y + f0.z*f0.z + f0.w*f0.w
          + f1.x*f1.x + f1.y*f1.y + f1.z*f1.z + f1.w*f1.w
          + f2.x*f2.x + f2.y*f2.y + f2.z*f2.z + f2.w*f2.w
          + f3.x*f3.x + f3.y*f3.y + f3.z*f3.z + f3.w*f3.w;
  s += __shfl_xor(s, 1);
  s += __shfl_xor(s, 2);
  if (q == 0) bnorm[row] = s;
  union { _Float16 h[16]; uint4 u[2]; } o;
  o.h[0]=(_Float16)f0.x; o.h[1]=(_Float16)f0.y; o.h[2]=(_Float16)f0.z; o.h[3]=(_Float16)f0.w;
  o.h[4]=(_Float16)f1.x; o.h[5]=(_Float16)f1.y; o.h[6]=(_Float16)f1.z; o.h[7]=(_Float16)f1.w;
  o.h[8]=(_Float16)f2.x; o.h[9]=(_Float16)f2.y; o.h[10]=(_Float16)f2.z; o.h[11]=(_Float16)f2.w;
  o.h[12]=(_Float16)f3.x; o.h[13]=(_Float16)f3.y; o.h[14]=(_Float16)f3.z; o.h[15]=(_Float16)f3.w;
  uint4* dst = (uint4*)(B16 + (size_t)row * DIM + q * 16);
  dst[0] = o.u[0]; dst[1] = o.u[1];
}

// ---------------- prep: xnorm ----------------
__global__ __launch_bounds__(256) void k_prep_x(const float* __restrict__ x,
                                                float* __restrict__ xnorm) {
  int gid = blockIdx.x * 256 + threadIdx.x;   // 4 threads per x row, 8192 total
  int row = gid >> 2, q = gid & 3;
  const float4* src = (const float4*)(x + (size_t)row * DIM + q * 16);
  float4 f0 = src[0], f1 = src[1], f2 = src[2], f3 = src[3];
  float s = f0.x*f0.x + f0.y*f0.y + f0.z*f0.z + f0.w*f0.w
          + f1.x*f1.x + f1.y*f1.y + f1.z*f1.z + f1.w*f1.w
          + f2.x*f2.x + f2.y*f2.y + f2.z*f2.z + f2.w*f2.w
          + f3.x*f3.x + f3.y*f3.y + f3.z*f3.z + f3.w*f3.w;
  s += __shfl_xor(s, 1);
  s += __shfl_xor(s, 2);
  if (q == 0) xnorm[row] = s;
}

// ---------------- main: MFMA d2 tiles + wave-local top-11 ----------------
// grid: (PPART, NR/128). Each workgroup: 128 rows x 2048 cols.
// Wave w owns rows [wgrow + 32w, +32); selection state is wave-local (no
// __syncthreads in the selection path -- only staging barriers).
__global__ __launch_bounds__(256) void k_main(const float* __restrict__ x,
                                              const _Float16* __restrict__ B16,
                                              const float* __restrict__ bnorm,
                                              const float* __restrict__ xnorm,
                                              float* __restrict__ cand) {
  __shared__ __align__(16) _Float16 Bs[CHUNK * BSTRIDE];
  __shared__ float bns[CHUNK];
  __shared__ float thr_s[4][32];
  __shared__ float bucket[4][32][CAP + 1];   // +1 stride: conflict-free owner scan
  __shared__ int bcnt[4][32];
  __shared__ unsigned bovf[4];

  const int tid = threadIdx.x;
  const int w = tid >> 6, lane = tid & 63;
  const int quad = lane >> 4, l15 = lane & 15;
  const int rowbase = blockIdx.y * 128 + w * 32;
  const int pbase = blockIdx.x * PART_COLS;

  if (lane < 32) { thr_s[w][lane] = __builtin_inff(); bcnt[w][lane] = 0; }
  if (lane == 0) bovf[w] = 0;

  // A fragments (f16) + xnorms, register-resident for the whole kernel.
  // A-operand layout (16x16x32): A[m = lane&15][k = quad*8 + j]
  v8h afrag[2][2];
  float xn[2][4];
#pragma unroll
  for (int rt = 0; rt < 2; ++rt) {
    const float* xr = x + (size_t)(rowbase + rt * 16 + l15) * DIM;
#pragma unroll
    for (int ks = 0; ks < 2; ++ks) {
      const float4* xp = (const float4*)(xr + ks * 32 + quad * 8);
      float4 a0 = xp[0], a1 = xp[1];
      v8h h;
      h[0]=(_Float16)a0.x; h[1]=(_Float16)a0.y; h[2]=(_Float16)a0.z; h[3]=(_Float16)a0.w;
      h[4]=(_Float16)a1.x; h[5]=(_Float16)a1.y; h[6]=(_Float16)a1.z; h[7]=(_Float16)a1.w;
      afrag[rt][ks] = h;
    }
#pragma unroll
    for (int reg = 0; reg < 4; ++reg)
      xn[rt][reg] = xnorm[rowbase + rt * 16 + quad * 4 + reg];
  }

  // register-resident top-11 list (owner lanes < 32 use it)
  float lst[KSEL];
#pragma unroll
  for (int i = 0; i < KSEL; ++i) lst[i] = __builtin_inff();
  float lmax = __builtin_inff();
  int amax = 0;

  for (int c = 0; c < NCHUNK; ++c) {
    const int cb = pbase + c * CHUNK;
    __syncthreads();   // Bs free (all waves done with previous chunk's MFMA)
    {
      // stage 128 cols x 64 k (f16) into padded LDS; 2 threads per col
      int brow = tid >> 1, hf = tid & 1;
      const uint4* src = (const uint4*)(B16 + (size_t)(cb + brow) * DIM + hf * 32);
      uint4 v0 = src[0], v1 = src[1], v2 = src[2], v3 = src[3];
      uint4* dst = (uint4*)(Bs + brow * BSTRIDE + hf * 32);
      dst[0] = v0; dst[1] = v1; dst[2] = v2; dst[3] = v3;
      if (tid < CHUNK) bns[tid] = bnorm[cb + tid];
    }
    __syncthreads();   // staged

    // MFMA: 2 row-tiles x 8 col-tiles x 2 k-steps
    v4f acc[2][8];
#pragma unroll
    for (int rt = 0; rt < 2; ++rt)
#pragma unroll
      for (int ct = 0; ct < 8; ++ct)
        acc[rt][ct] = (v4f)(0.0f);
#pragma unroll
    for (int ct = 0; ct < 8; ++ct) {
      v8h b0 = *(const v8h*)(Bs + (ct * 16 + l15) * BSTRIDE + quad * 8);
      v8h b1 = *(const v8h*)(Bs + (ct * 16 + l15) * BSTRIDE + 32 + quad * 8);
#pragma unroll
      for (int rt = 0; rt < 2; ++rt) {
        acc[rt][ct] = __builtin_amdgcn_mfma_f32_16x16x32_f16(afrag[rt][0], b0, acc[rt][ct], 0, 0, 0);
        acc[rt][ct] = __builtin_amdgcn_mfma_f32_16x16x32_f16(afrag[rt][1], b1, acc[rt][ct], 0, 0, 0);
      }
    }

    // wave-local selection: push candidates below row threshold into per-row
    // buckets; owner lane processes; rescan on overflow (bounded, thr monotone)
    unsigned long long done = 0ULL;
    bool again = true;
    int guard = 0;
    while (again && guard < 64) {
      ++guard;
      float thrc[2][4];
#pragma unroll
      for (int rt = 0; rt < 2; ++rt)
#pragma unroll
        for (int reg = 0; reg < 4; ++reg)
          thrc[rt][reg] = thr_s[w][rt * 16 + quad * 4 + reg];
#pragma unroll
      for (int ct = 0; ct < 8; ++ct) {
        float bn = bns[ct * 16 + l15];
#pragma unroll
        for (int rt = 0; rt < 2; ++rt) {
#pragma unroll
          for (int reg = 0; reg < 4; ++reg) {
            int v = rt * 32 + ct * 4 + reg;
            if (done & (1ULL << v)) continue;
            float d2 = xn[rt][reg] + bn - 2.0f * acc[rt][ct][reg];
            d2 = fmaxf(d2, 0.0f);
            if (d2 < thrc[rt][reg]) {
              int r = rt * 16 + quad * 4 + reg;
              int idx = atomicAdd(&bcnt[w][r], 1);
              if (idx < CAP) { bucket[w][r][idx] = d2; done |= (1ULL << v); }
              else atomicOr(&bovf[w], 1u << r);
            } else {
              done |= (1ULL << v);   // thr only decreases -> never passes later
            }
          }
        }
      }
      __threadfence_block();
      if (lane < 32) {
        int n = bcnt[w][lane]; if (n > CAP) n = CAP;
        for (int i = 0; i < n; ++i) {
          float vv = bucket[w][lane][i];
          if (vv < lmax) {
#pragma unroll
            for (int j = 0; j < KSEL; ++j) if (j == amax) lst[j] = vv;
            lmax = lst[0]; amax = 0;
#pragma unroll
            for (int j = 1; j < KSEL; ++j) if (lst[j] > lmax) { lmax = lst[j]; amax = j; }
          }
        }
        thr_s[w][lane] = lmax;
        bcnt[w][lane] = 0;
      }
      __threadfence_block();
      unsigned m = bovf[w];
      __threadfence_block();
      if (lane == 0) bovf[w] = 0;
      __threadfence_block();
      again = (m != 0);
    }
  }

  if (lane < 32) {
    int grow = rowbase + lane;
    float* dst = cand + ((size_t)grow * PPART + blockIdx.x) * KSEL;
#pragma unroll
    for (int i = 0; i < KSEL; ++i) dst[i] = lst[i];
  }
}

// ---------------- merge: 64x11 candidates -> top-11 -> output ----------------
__global__ __launch_bounds__(256) void k_merge(const float* __restrict__ cand,
                                               float* __restrict__ out) {
  int row = blockIdx.x * 256 + threadIdx.x;
  const float4* src = (const float4*)(cand + (size_t)row * (PPART * KSEL)); // 704 floats
  float lst[KSEL];
#pragma unroll
  for (int i = 0; i < KSEL; ++i) lst[i] = __builtin_inff();
  float lmax = __builtin_inff();
  int amax = 0;
  auto ins = [&](float vv) {
    if (vv < lmax) {
#pragma unroll
      for (int j = 0; j < KSEL; ++j) if (j == amax) lst[j] = vv;
      lmax = lst[0]; amax = 0;
#pragma unroll
      for (int j = 1; j < KSEL; ++j) if (lst[j] > lmax) { lmax = lst[j]; amax = j; }
    }
  };
  for (int i = 0; i < (PPART * KSEL) / 4; ++i) {
    float4 v = src[i];
    ins(v.x); ins(v.y); ins(v.z); ins(v.w);
  }
  float vmin = lst[0];
#pragma unroll
  for (int j = 1; j < KSEL; ++j) vmin = fminf(vmin, lst[j]);
  float s = 0.0f;
#pragma unroll
  for (int j = 0; j < KSEL; ++j) s += sqrtf(lst[j]);
  s -= sqrtf(vmin);                       // drop the self-match
  out[row] = log1pf(s * 0.1f);            // mean over k=10, log1p
}

extern "C" void kernel_launch(void* const* d_in, const int* in_sizes, int n_in,
                              void* d_out, int out_size, void* d_ws, size_t ws_size,
                              hipStream_t stream) {
  (void)in_sizes; (void)n_in; (void)out_size; (void)ws_size;
  const float* x   = (const float*)d_in[0];   // 2048 x 64
  const float* buf = (const float*)d_in[1];   // 131072 x 64
  float* out = (float*)d_out;

  // workspace carve (all 16B aligned); total ~22.0 MB
  char* ws = (char*)d_ws;
  _Float16* B16 = (_Float16*)ws;                       // 16,777,216 B
  float* bnorm  = (float*)(ws + 16777216);             //    524,288 B
  float* xnorm  = (float*)(ws + 17301504);             //      8,192 B
  float* cand   = (float*)(ws + 17309696);             //  5,767,168 B

  k_prep_b<<<dim3(2048), dim3(256), 0, stream>>>(buf, B16, bnorm);
  k_prep_x<<<dim3(32),   dim3(256), 0, stream>>>(x, xnorm);
  k_main<<<dim3(PPART, NR / 128), dim3(256), 0, stream>>>(x, B16, bnorm, xnorm, cand);
  k_merge<<<dim3(NR / 256), dim3(256), 0, stream>>>(cand, out);
}